// Round 1
// 687.271 us; speedup vs baseline: 1.0385x; 1.0385x over previous
//
#include <hip/hip_runtime.h>
#include <stdint.h>
#include <stddef.h>

// Problem constants (from reference)
constexpr int N_NODES = 100000;
constexpr int BATCH   = 1024;
constexpr int LAT     = 128;   // LATENT == NODE_DIM
constexpr int INDIM   = 384;   // NODE_DIM + 2*LATENT
constexpr int FFNIN   = 512;   // LATENT + INDIM
constexpr int NB_MAX  = 512;   // max neighbors/row (mean ~50, binomial max ~85)

typedef unsigned int u32x4 __attribute__((ext_vector_type(4)));

__device__ __forceinline__ float dot4(float4 a, float4 b) {
    return a.x * b.x + a.y * b.y + a.z * b.z + a.w * b.w;
}

// ---------------------------------------------------------------------------
// One block per batch row, fully fused, zero workspace.
// neighbor_mask is int32-encoded bool (4 B/elem) — established empirically:
// byte-mode decode fails (absmax 0.135), int32 decode passes (absmax 1.95e-3).
// Do NOT revert to byte decode.
//
// Structure (this round):
//   phase A (overlapped): wave 0 computes q = Wq@qin+bq in regs, sbias,
//                         qk = q@Wk via __shfl broadcast (no LDS sync);
//                         waves 1-5 scan the mask row -> LDS neighbor list.
//   phase B: fused sparse scores + online-softmax aggregation — each wave
//            keeps (m, sum_e, u_partial[6]) and REUSES the feature regs
//            loaded for the dot product (second gather pass eliminated).
//   phase C: 6-wave softmax combine; Wv/W1/W2 matvecs 3-way split across
//            all 384 threads (INDIM = 3*128).
// ---------------------------------------------------------------------------
__global__ __launch_bounds__(384) void fused_graph_attn_kernel(
    const float* __restrict__ x,   const float* __restrict__ mem,
    const float* __restrict__ dtv, const float* __restrict__ ttv,
    const uint32_t* __restrict__ mask, const int* __restrict__ tar_idx,
    const float* __restrict__ Wq, const float* __restrict__ bq,
    const float* __restrict__ Wk, const float* __restrict__ bk,
    const float* __restrict__ Wv, const float* __restrict__ bv,
    const float* __restrict__ W1, const float* __restrict__ b1,
    const float* __restrict__ W2, const float* __restrict__ b2,
    float* __restrict__ out)
{
    const int b    = blockIdx.x;
    const int tid  = threadIdx.x;
    const int lane = tid & 63;
    const int wave = tid >> 6;

    __shared__ int cnt;
    __shared__ int jl[NB_MAX];
    __shared__ __align__(16) float qin[INDIM];
    __shared__ __align__(16) float qk[INDIM];
    __shared__ __align__(16) float u[INDIM];
    __shared__ __align__(16) float zbuf[FFNIN];
    __shared__ __align__(16) float hbuf[LAT];
    __shared__ __align__(16) float upart[6][INDIM];   // also reused as matvec partials
    __shared__ float wm[6], ws[6], sbias_sh;

    const int idx = tar_idx[b];
    if (tid == 0) cnt = 0;

    // ---- load q_input = [x[idx], memory[idx], tar_t_vec[b]] ----
    if (tid < 128)      qin[tid] = x[(size_t)idx * LAT + tid];
    else if (tid < 256) qin[tid] = mem[(size_t)idx * LAT + (tid - 128)];
    else                qin[tid] = ttv[(size_t)b * LAT + (tid - 256)];
    __syncthreads();   // qin + cnt=0 visible

    if (wave == 0) {
        // ---- q rows lane & lane+64, fully in registers ----
        const float4* qin4 = (const float4*)qin;
        const float4* r0 = (const float4*)(Wq + (size_t)lane * INDIM);
        const float4* r1 = (const float4*)(Wq + (size_t)(lane + 64) * INDIM);
        float a0 = bq[lane], a1 = bq[lane + 64];
        #pragma unroll 4
        for (int i = 0; i < INDIM / 4; ++i) {
            float4 qi = qin4[i];
            a0 += dot4(r0[i], qi);
            a1 += dot4(r1[i], qi);
        }
        // ---- sbias = dot(q, bk) ----
        float sb = a0 * bk[lane] + a1 * bk[lane + 64];
        #pragma unroll
        for (int off = 1; off < 64; off <<= 1) sb += __shfl_xor(sb, off, 64);
        if (lane == 0) sbias_sh = sb;
        // ---- qk[j] = sum_l q[l] * Wk[l][j], q broadcast via shfl ----
        float qt[6] = {0.f, 0.f, 0.f, 0.f, 0.f, 0.f};
        for (int l = 0; l < 64; ++l) {
            float qd = __shfl(a0, l, 64);
            const float* wkp = Wk + (size_t)l * INDIM + lane;
            #pragma unroll
            for (int t = 0; t < 6; ++t) qt[t] += qd * wkp[64 * t];
        }
        for (int l = 0; l < 64; ++l) {
            float qd = __shfl(a1, l, 64);
            const float* wkp = Wk + (size_t)(l + 64) * INDIM + lane;
            #pragma unroll
            for (int t = 0; t < 6; ++t) qt[t] += qd * wkp[64 * t];
        }
        #pragma unroll
        for (int t = 0; t < 6; ++t) qk[lane + 64 * t] = qt[t];
    } else {
        // ---- waves 1-5 scan this row's mask (int32 bools, 400000 B/row) ----
        const u32x4* row = (const u32x4*)(mask + (size_t)b * N_NODES);
        #pragma unroll 2
        for (int i = tid - 64; i < N_NODES / 4; i += 320) {
            u32x4 v = __builtin_nontemporal_load(row + i);  // single-use stream
            if (v.x | v.y | v.z | v.w) {
                uint32_t w[4] = {v.x, v.y, v.z, v.w};
                #pragma unroll
                for (int wi = 0; wi < 4; ++wi) {
                    if (w[wi]) {
                        int slot = atomicAdd(&cnt, 1);
                        if (slot < NB_MAX) jl[slot] = i * 4 + wi;
                    }
                }
            }
        }
    }
    __syncthreads();
    if (tid == 0 && cnt == 0) { jl[0] = idx; cnt = 1; }  // no-neighbor -> self
    __syncthreads();
    const int nb = cnt < NB_MAX ? cnt : NB_MAX;

    // ---- fused sparse scores + online-softmax weighted aggregation ----
    const float scale = 0.088388347648318447f;  // 1/sqrt(128)
    const float sb = sbias_sh;
    float qkr[6];
    #pragma unroll
    for (int k = 0; k < 6; ++k) qkr[k] = qk[lane + 64 * k];

    float m = -INFINITY, ssum = 0.f;
    float ua[6] = {0.f, 0.f, 0.f, 0.f, 0.f, 0.f};
    for (int jj = wave; jj < nb; jj += 6) {
        const int j = jl[jj];
        const float* xp = x   + (size_t)j * LAT;
        const float* mp = mem + (size_t)j * LAT;
        const float* dp = dtv + (size_t)j * LAT;
        const float f0 = xp[lane], f1 = xp[lane + 64];
        const float f2 = mp[lane], f3 = mp[lane + 64];
        const float f4 = dp[lane], f5 = dp[lane + 64];
        float p = qkr[0] * f0 + qkr[1] * f1 + qkr[2] * f2
                + qkr[3] * f3 + qkr[4] * f4 + qkr[5] * f5;
        #pragma unroll
        for (int off = 1; off < 64; off <<= 1) p += __shfl_xor(p, off, 64);
        const float s    = (p + sb) * scale;
        const float mn   = fmaxf(m, s);
        const float corr = __expf(m - mn);   // 0 on first neighbor (m = -inf)
        const float e    = __expf(s - mn);
        ssum = ssum * corr + e;
        ua[0] = ua[0] * corr + e * f0;  ua[1] = ua[1] * corr + e * f1;
        ua[2] = ua[2] * corr + e * f2;  ua[3] = ua[3] * corr + e * f3;
        ua[4] = ua[4] * corr + e * f4;  ua[5] = ua[5] * corr + e * f5;
        m = mn;
    }
    if (lane == 0) { wm[wave] = m; ws[wave] = ssum; }
    #pragma unroll
    for (int k = 0; k < 6; ++k) upart[wave][lane + 64 * k] = ua[k];
    __syncthreads();

    // ---- combine 6 per-wave (m, s, u) triples; all 384 threads ----
    {
        float mstar = wm[0];
        #pragma unroll
        for (int w = 1; w < 6; ++w) mstar = fmaxf(mstar, wm[w]);
        float num = 0.f, den = 0.f;
        #pragma unroll
        for (int w = 0; w < 6; ++w) {
            const float c = __expf(wm[w] - mstar);  // 0 for empty waves (wm=-inf)
            num += c * upart[w][tid];
            den += c * ws[w];
        }
        u[tid] = num / den;
    }
    __syncthreads();

    float* part = &upart[0][0];       // reuse as matvec partial buffer
    const int o  = tid & 127;
    const int pp = tid >> 7;          // 0..2; uniform per wave-pair

    // ---- agg = Wv @ u + bv, 3-way split (INDIM = 3*128) ----
    {
        const float4* wr = (const float4*)(Wv + (size_t)o * INDIM);
        const float4* uv = (const float4*)u;
        const int i0 = pp * 32;
        float acc = 0.f;
        #pragma unroll 4
        for (int i = i0; i < i0 + 32; ++i) acc += dot4(wr[i], uv[i]);
        part[pp * 128 + o] = acc;
    }
    zbuf[LAT + tid] = qin[tid];
    __syncthreads();
    if (tid < 128) zbuf[tid] = bv[tid] + part[tid] + part[128 + tid] + part[256 + tid];
    __syncthreads();

    // ---- h = relu(W1 @ zbuf + b1), 3-way split (128 float4: 43/43/42) ----
    {
        const float4* wr = (const float4*)(W1 + (size_t)o * FFNIN);
        const float4* zv = (const float4*)zbuf;
        const int i0 = pp * 43;
        const int i1 = (pp == 2) ? 128 : i0 + 43;
        float acc = 0.f;
        #pragma unroll 4
        for (int i = i0; i < i1; ++i) acc += dot4(wr[i], zv[i]);
        part[pp * 128 + o] = acc;
    }
    __syncthreads();
    if (tid < 128)
        hbuf[tid] = fmaxf(b1[tid] + part[tid] + part[128 + tid] + part[256 + tid], 0.f);
    __syncthreads();

    // ---- out = W2 @ h + b2, 3-way split (32 float4: 11/11/10) ----
    {
        const float4* wr = (const float4*)(W2 + (size_t)o * LAT);
        const float4* hv = (const float4*)hbuf;
        const int i0 = pp * 11;
        const int i1 = (pp == 2) ? 32 : i0 + 11;
        float acc = 0.f;
        #pragma unroll 4
        for (int i = i0; i < i1; ++i) acc += dot4(wr[i], hv[i]);
        part[pp * 128 + o] = acc;
    }
    __syncthreads();
    if (tid < 128)
        out[(size_t)b * LAT + tid] = b2[tid] + part[tid] + part[128 + tid] + part[256 + tid];
}

extern "C" void kernel_launch(void* const* d_in, const int* in_sizes, int n_in,
                              void* d_out, int out_size, void* d_ws, size_t ws_size,
                              hipStream_t stream) {
    const float*    x    = (const float*)d_in[0];
    const float*    mem  = (const float*)d_in[1];
    const float*    dtv  = (const float*)d_in[2];
    const float*    ttv  = (const float*)d_in[3];
    const uint32_t* mask = (const uint32_t*)d_in[4];  // bool as int32 (verified R1-R3)
    const int*      tidx = (const int*)d_in[5];
    const float*    Wq   = (const float*)d_in[6];
    const float*    bq   = (const float*)d_in[7];
    const float*    Wk   = (const float*)d_in[8];
    const float*    bk   = (const float*)d_in[9];
    const float*    Wv   = (const float*)d_in[10];
    const float*    bv   = (const float*)d_in[11];
    const float*    W1   = (const float*)d_in[12];
    const float*    b1   = (const float*)d_in[13];
    const float*    W2   = (const float*)d_in[14];
    const float*    b2   = (const float*)d_in[15];
    float* out = (float*)d_out;

    fused_graph_attn_kernel<<<BATCH, 384, 0, stream>>>(
        x, mem, dtv, ttv, mask, tidx, Wq, bq, Wk, bk, Wv, bv, W1, b1, W2, b2,
        out);
}

// Round 2
// 684.405 us; speedup vs baseline: 1.0429x; 1.0042x over previous
//
#include <hip/hip_runtime.h>
#include <stdint.h>
#include <stddef.h>

// Problem constants (from reference)
constexpr int N_NODES = 100000;
constexpr int BATCH   = 1024;
constexpr int LAT     = 128;   // LATENT == NODE_DIM
constexpr int INDIM   = 384;   // NODE_DIM + 2*LATENT
constexpr int FFNIN   = 512;   // LATENT + INDIM
constexpr int NB_MAX  = 512;   // max neighbors/row (mean ~50, binomial max ~85)
constexpr int NV      = N_NODES / 4;  // 25000 u32x4 words per mask row

typedef unsigned int u32x4 __attribute__((ext_vector_type(4)));

__device__ __forceinline__ float dot4(float4 a, float4 b) {
    return a.x * b.x + a.y * b.y + a.z * b.z + a.w * b.w;
}

// ---------------------------------------------------------------------------
// One block per batch row, fully fused, zero workspace.
// neighbor_mask is int32-encoded bool (4 B/elem) — established empirically:
// byte-mode decode fails (absmax 0.135), int32 decode passes (absmax 1.95e-3).
// Do NOT revert to byte decode.
//
// Structure (this round):
//   phase S: ALL 6 waves scan the mask row, manual 4-deep unroll — four
//            independent nontemporal u32x4 loads issued before any branch
//            (scan was ~2x off HBM floor; MLP was the suspect).
//   phase Q: q = Wq@qin+bq (3-way split, all 384 threads), qk = q@Wk
//            (coalesced, one output/thread), sbias = dot(q,bk) (wave 0).
//   phase B: fused sparse scores + online-softmax aggregation (per-wave
//            m/sum/u-partial, feature regs reused — single gather pass).
//   phase C: 6-wave combine; Wv/W1/W2 matvecs 3-way split across 384 threads.
// ---------------------------------------------------------------------------
__global__ __launch_bounds__(384) void fused_graph_attn_kernel(
    const float* __restrict__ x,   const float* __restrict__ mem,
    const float* __restrict__ dtv, const float* __restrict__ ttv,
    const uint32_t* __restrict__ mask, const int* __restrict__ tar_idx,
    const float* __restrict__ Wq, const float* __restrict__ bq,
    const float* __restrict__ Wk, const float* __restrict__ bk,
    const float* __restrict__ Wv, const float* __restrict__ bv,
    const float* __restrict__ W1, const float* __restrict__ b1,
    const float* __restrict__ W2, const float* __restrict__ b2,
    float* __restrict__ out)
{
    const int b    = blockIdx.x;
    const int tid  = threadIdx.x;
    const int lane = tid & 63;
    const int wave = tid >> 6;

    __shared__ int cnt;
    __shared__ int jl[NB_MAX];
    __shared__ __align__(16) float qin[INDIM];
    __shared__ __align__(16) float qv[LAT];
    __shared__ __align__(16) float qk[INDIM];
    __shared__ __align__(16) float u[INDIM];
    __shared__ __align__(16) float zbuf[FFNIN];
    __shared__ __align__(16) float hbuf[LAT];
    __shared__ __align__(16) float upart[6][INDIM];   // also matvec partial scratch
    __shared__ float wm[6], ws[6], sbias_sh;

    const int idx = tar_idx[b];
    if (tid == 0) cnt = 0;

    // ---- load q_input = [x[idx], memory[idx], tar_t_vec[b]] ----
    if (tid < 128)      qin[tid] = x[(size_t)idx * LAT + tid];
    else if (tid < 256) qin[tid] = mem[(size_t)idx * LAT + (tid - 128)];
    else                qin[tid] = ttv[(size_t)b * LAT + (tid - 256)];
    __syncthreads();   // qin + cnt=0 visible

    // ---- phase S: scan this row's mask (int32 bools, 400000 B/row) ----
    {
        const u32x4* row = (const u32x4*)(mask + (size_t)b * N_NODES);
        auto proc = [&](u32x4 v, int base) {
            if (v.x | v.y | v.z | v.w) {
                uint32_t w[4] = {v.x, v.y, v.z, v.w};
                #pragma unroll
                for (int wi = 0; wi < 4; ++wi) {
                    if (w[wi]) {
                        int slot = atomicAdd(&cnt, 1);
                        if (slot < NB_MAX) jl[slot] = base * 4 + wi;
                    }
                }
            }
        };
        int i = tid;
        // 4-deep: all four loads issue before any use (one vmcnt region)
        for (; i + 3 * 384 < NV; i += 4 * 384) {
            u32x4 v0 = __builtin_nontemporal_load(row + i);
            u32x4 v1 = __builtin_nontemporal_load(row + i + 384);
            u32x4 v2 = __builtin_nontemporal_load(row + i + 768);
            u32x4 v3 = __builtin_nontemporal_load(row + i + 1152);
            proc(v0, i);
            proc(v1, i + 384);
            proc(v2, i + 768);
            proc(v3, i + 1152);
        }
        for (; i < NV; i += 384) {
            u32x4 v = __builtin_nontemporal_load(row + i);
            proc(v, i);
        }
    }
    __syncthreads();
    if (tid == 0 && cnt == 0) { jl[0] = idx; cnt = 1; }  // no-neighbor -> self
    __syncthreads();
    const int nb = cnt < NB_MAX ? cnt : NB_MAX;

    float* part = &upart[0][0];       // matvec partial scratch (>=384 floats)
    const int o  = tid & 127;
    const int pp = tid >> 7;          // 0..2; uniform per wave-pair

    // ---- phase Q: q = Wq @ qin + bq, 3-way split (INDIM = 3*128) ----
    {
        const float4* wr  = (const float4*)(Wq + (size_t)o * INDIM);
        const float4* qi4 = (const float4*)qin;
        const int i0 = pp * 32;
        float acc = 0.f;
        #pragma unroll 4
        for (int i = i0; i < i0 + 32; ++i) acc += dot4(wr[i], qi4[i]);
        part[pp * 128 + o] = acc;
    }
    __syncthreads();
    if (tid < 128) qv[tid] = bq[tid] + part[tid] + part[128 + tid] + part[256 + tid];
    __syncthreads();

    // ---- qk[j] = sum_d qv[d] * Wk[d][j]  (coalesced Wk reads) ----
    {
        float acc = 0.f;
        #pragma unroll 8
        for (int d = 0; d < LAT; ++d) acc += qv[d] * Wk[(size_t)d * INDIM + tid];
        qk[tid] = acc;
    }
    // ---- sbias = dot(q, bk) (wave 0) ----
    if (wave == 0) {
        float p = qv[lane] * bk[lane] + qv[lane + 64] * bk[lane + 64];
        #pragma unroll
        for (int off = 1; off < 64; off <<= 1) p += __shfl_xor(p, off, 64);
        if (lane == 0) sbias_sh = p;
    }
    __syncthreads();

    // ---- phase B: fused sparse scores + online-softmax aggregation ----
    const float scale = 0.088388347648318447f;  // 1/sqrt(128)
    const float sb = sbias_sh;
    float qkr[6];
    #pragma unroll
    for (int k = 0; k < 6; ++k) qkr[k] = qk[lane + 64 * k];

    float m = -INFINITY, ssum = 0.f;
    float ua[6] = {0.f, 0.f, 0.f, 0.f, 0.f, 0.f};
    for (int jj = wave; jj < nb; jj += 6) {
        const int j = jl[jj];
        const float* xp = x   + (size_t)j * LAT;
        const float* mp = mem + (size_t)j * LAT;
        const float* dp = dtv + (size_t)j * LAT;
        const float f0 = xp[lane], f1 = xp[lane + 64];
        const float f2 = mp[lane], f3 = mp[lane + 64];
        const float f4 = dp[lane], f5 = dp[lane + 64];
        float p = qkr[0] * f0 + qkr[1] * f1 + qkr[2] * f2
                + qkr[3] * f3 + qkr[4] * f4 + qkr[5] * f5;
        #pragma unroll
        for (int off = 1; off < 64; off <<= 1) p += __shfl_xor(p, off, 64);
        const float s    = (p + sb) * scale;
        const float mn   = fmaxf(m, s);
        const float corr = __expf(m - mn);   // 0 on first neighbor (m = -inf)
        const float e    = __expf(s - mn);
        ssum = ssum * corr + e;
        ua[0] = ua[0] * corr + e * f0;  ua[1] = ua[1] * corr + e * f1;
        ua[2] = ua[2] * corr + e * f2;  ua[3] = ua[3] * corr + e * f3;
        ua[4] = ua[4] * corr + e * f4;  ua[5] = ua[5] * corr + e * f5;
        m = mn;
    }
    if (lane == 0) { wm[wave] = m; ws[wave] = ssum; }
    #pragma unroll
    for (int k = 0; k < 6; ++k) upart[wave][lane + 64 * k] = ua[k];
    __syncthreads();

    // ---- phase C: combine 6 per-wave (m, s, u) triples; all 384 threads ----
    {
        float mstar = wm[0];
        #pragma unroll
        for (int w = 1; w < 6; ++w) mstar = fmaxf(mstar, wm[w]);
        float num = 0.f, den = 0.f;
        #pragma unroll
        for (int w = 0; w < 6; ++w) {
            const float c = __expf(wm[w] - mstar);  // 0 for empty waves (wm=-inf)
            num += c * upart[w][tid];
            den += c * ws[w];
        }
        u[tid] = num / den;
    }
    __syncthreads();

    // ---- agg = Wv @ u + bv, 3-way split (INDIM = 3*128) ----
    {
        const float4* wr = (const float4*)(Wv + (size_t)o * INDIM);
        const float4* uv = (const float4*)u;
        const int i0 = pp * 32;
        float acc = 0.f;
        #pragma unroll 4
        for (int i = i0; i < i0 + 32; ++i) acc += dot4(wr[i], uv[i]);
        part[pp * 128 + o] = acc;
    }
    zbuf[LAT + tid] = qin[tid];
    __syncthreads();
    if (tid < 128) zbuf[tid] = bv[tid] + part[tid] + part[128 + tid] + part[256 + tid];
    __syncthreads();

    // ---- h = relu(W1 @ zbuf + b1), 3-way split (128 float4: 43/43/42) ----
    {
        const float4* wr = (const float4*)(W1 + (size_t)o * FFNIN);
        const float4* zv = (const float4*)zbuf;
        const int i0 = pp * 43;
        const int i1 = (pp == 2) ? 128 : i0 + 43;
        float acc = 0.f;
        #pragma unroll 4
        for (int i = i0; i < i1; ++i) acc += dot4(wr[i], zv[i]);
        part[pp * 128 + o] = acc;
    }
    __syncthreads();
    if (tid < 128)
        hbuf[tid] = fmaxf(b1[tid] + part[tid] + part[128 + tid] + part[256 + tid], 0.f);
    __syncthreads();

    // ---- out = W2 @ h + b2, 3-way split (32 float4: 11/11/10) ----
    {
        const float4* wr = (const float4*)(W2 + (size_t)o * LAT);
        const float4* hv = (const float4*)hbuf;
        const int i0 = pp * 11;
        const int i1 = (pp == 2) ? 32 : i0 + 11;
        float acc = 0.f;
        #pragma unroll 4
        for (int i = i0; i < i1; ++i) acc += dot4(wr[i], hv[i]);
        part[pp * 128 + o] = acc;
    }
    __syncthreads();
    if (tid < 128)
        out[(size_t)b * LAT + tid] = b2[tid] + part[tid] + part[128 + tid] + part[256 + tid];
}

extern "C" void kernel_launch(void* const* d_in, const int* in_sizes, int n_in,
                              void* d_out, int out_size, void* d_ws, size_t ws_size,
                              hipStream_t stream) {
    const float*    x    = (const float*)d_in[0];
    const float*    mem  = (const float*)d_in[1];
    const float*    dtv  = (const float*)d_in[2];
    const float*    ttv  = (const float*)d_in[3];
    const uint32_t* mask = (const uint32_t*)d_in[4];  // bool as int32 (verified R1-R3)
    const int*      tidx = (const int*)d_in[5];
    const float*    Wq   = (const float*)d_in[6];
    const float*    bq   = (const float*)d_in[7];
    const float*    Wk   = (const float*)d_in[8];
    const float*    bk   = (const float*)d_in[9];
    const float*    Wv   = (const float*)d_in[10];
    const float*    bv   = (const float*)d_in[11];
    const float*    W1   = (const float*)d_in[12];
    const float*    b1   = (const float*)d_in[13];
    const float*    W2   = (const float*)d_in[14];
    const float*    b2   = (const float*)d_in[15];
    float* out = (float*)d_out;

    fused_graph_attn_kernel<<<BATCH, 384, 0, stream>>>(
        x, mem, dtv, ttv, mask, tidx, Wq, bq, Wk, bk, Wv, bv, W1, b1, W2, b2,
        out);
}

// Round 3
// 680.813 us; speedup vs baseline: 1.0484x; 1.0053x over previous
//
#include <hip/hip_runtime.h>
#include <stdint.h>
#include <stddef.h>

// Problem constants (from reference)
constexpr int N_NODES = 100000;
constexpr int BATCH   = 1024;
constexpr int LAT     = 128;   // LATENT == NODE_DIM
constexpr int INDIM   = 384;   // NODE_DIM + 2*LATENT
constexpr int FFNIN   = 512;   // LATENT + INDIM
constexpr int NB_MAX  = 512;   // max neighbors/row (mean ~50, binomial max ~85)
constexpr int NV      = N_NODES / 4;  // 25000 u32x4 words per mask row

typedef unsigned int u32x4 __attribute__((ext_vector_type(4)));

__device__ __forceinline__ float dot4(float4 a, float4 b) {
    return a.x * b.x + a.y * b.y + a.z * b.z + a.w * b.w;
}

// ---------------------------------------------------------------------------
// One block per batch row, fully fused, zero workspace.
// neighbor_mask is int32-encoded bool (4 B/elem) — established empirically:
// byte-mode decode fails (absmax 0.135), int32 decode passes (absmax 1.95e-3).
// Do NOT revert to byte decode.
//
// Structure (this round):
//   phase S: all 6 waves scan the mask row (4-deep unrolled nontemporal
//            u32x4 loads; BW-saturated per R2 A/B — do not touch).
//   phase Q: q = Wq@qin+bq (3-way split), qk = q@Wk (coalesced, unroll 16),
//            sbias = dot(q,bk).
//   phase B: fused sparse scores + online-softmax aggregation with
//            (a) explicit 2-buffer register pipeline (fa/fb) so next
//                neighbor's 6 gathers issue before current update runs,
//            (b) wave-uniform single-exp path: s<=m -> no rescale, one exp;
//                s>m -> corr=exp(m-s), e=1 exactly.
//   phase C: 6-wave combine; Wv/W1/W2 matvecs 3-way split across 384 threads.
// ---------------------------------------------------------------------------
__global__ __launch_bounds__(384) void fused_graph_attn_kernel(
    const float* __restrict__ x,   const float* __restrict__ mem,
    const float* __restrict__ dtv, const float* __restrict__ ttv,
    const uint32_t* __restrict__ mask, const int* __restrict__ tar_idx,
    const float* __restrict__ Wq, const float* __restrict__ bq,
    const float* __restrict__ Wk, const float* __restrict__ bk,
    const float* __restrict__ Wv, const float* __restrict__ bv,
    const float* __restrict__ W1, const float* __restrict__ b1,
    const float* __restrict__ W2, const float* __restrict__ b2,
    float* __restrict__ out)
{
    const int b    = blockIdx.x;
    const int tid  = threadIdx.x;
    const int lane = tid & 63;
    const int wave = tid >> 6;

    __shared__ int cnt;
    __shared__ int jl[NB_MAX];
    __shared__ __align__(16) float qin[INDIM];
    __shared__ __align__(16) float qv[LAT];
    __shared__ __align__(16) float qk[INDIM];
    __shared__ __align__(16) float u[INDIM];
    __shared__ __align__(16) float zbuf[FFNIN];
    __shared__ __align__(16) float hbuf[LAT];
    __shared__ __align__(16) float upart[6][INDIM];   // also matvec partial scratch
    __shared__ float wm[6], ws[6], sbias_sh;

    const int idx = tar_idx[b];
    if (tid == 0) cnt = 0;

    // ---- load q_input = [x[idx], memory[idx], tar_t_vec[b]] ----
    if (tid < 128)      qin[tid] = x[(size_t)idx * LAT + tid];
    else if (tid < 256) qin[tid] = mem[(size_t)idx * LAT + (tid - 128)];
    else                qin[tid] = ttv[(size_t)b * LAT + (tid - 256)];
    __syncthreads();   // qin + cnt=0 visible

    // ---- phase S: scan this row's mask (int32 bools, 400000 B/row) ----
    {
        const u32x4* row = (const u32x4*)(mask + (size_t)b * N_NODES);
        auto proc = [&](u32x4 v, int base) {
            if (v.x | v.y | v.z | v.w) {
                uint32_t w[4] = {v.x, v.y, v.z, v.w};
                #pragma unroll
                for (int wi = 0; wi < 4; ++wi) {
                    if (w[wi]) {
                        int slot = atomicAdd(&cnt, 1);
                        if (slot < NB_MAX) jl[slot] = base * 4 + wi;
                    }
                }
            }
        };
        int i = tid;
        // 4-deep: all four loads issue before any use (one vmcnt region)
        for (; i + 3 * 384 < NV; i += 4 * 384) {
            u32x4 v0 = __builtin_nontemporal_load(row + i);
            u32x4 v1 = __builtin_nontemporal_load(row + i + 384);
            u32x4 v2 = __builtin_nontemporal_load(row + i + 768);
            u32x4 v3 = __builtin_nontemporal_load(row + i + 1152);
            proc(v0, i);
            proc(v1, i + 384);
            proc(v2, i + 768);
            proc(v3, i + 1152);
        }
        for (; i < NV; i += 384) {
            u32x4 v = __builtin_nontemporal_load(row + i);
            proc(v, i);
        }
    }
    __syncthreads();
    if (tid == 0 && cnt == 0) { jl[0] = idx; cnt = 1; }  // no-neighbor -> self
    __syncthreads();
    const int nb = cnt < NB_MAX ? cnt : NB_MAX;

    float* part = &upart[0][0];       // matvec partial scratch (>=384 floats)
    const int o  = tid & 127;
    const int pp = tid >> 7;          // 0..2; uniform per wave-pair

    // ---- phase Q: q = Wq @ qin + bq, 3-way split (INDIM = 3*128) ----
    {
        const float4* wr  = (const float4*)(Wq + (size_t)o * INDIM);
        const float4* qi4 = (const float4*)qin;
        const int i0 = pp * 32;
        float acc = 0.f;
        #pragma unroll 4
        for (int i = i0; i < i0 + 32; ++i) acc += dot4(wr[i], qi4[i]);
        part[pp * 128 + o] = acc;
    }
    __syncthreads();
    if (tid < 128) qv[tid] = bq[tid] + part[tid] + part[128 + tid] + part[256 + tid];
    __syncthreads();

    // ---- qk[j] = sum_d qv[d] * Wk[d][j]  (coalesced Wk reads) ----
    {
        float acc = 0.f;
        #pragma unroll 16
        for (int d = 0; d < LAT; ++d) acc += qv[d] * Wk[(size_t)d * INDIM + tid];
        qk[tid] = acc;
    }
    // ---- sbias = dot(q, bk) (wave 0) ----
    if (wave == 0) {
        float p = qv[lane] * bk[lane] + qv[lane + 64] * bk[lane + 64];
        #pragma unroll
        for (int off = 1; off < 64; off <<= 1) p += __shfl_xor(p, off, 64);
        if (lane == 0) sbias_sh = p;
    }
    __syncthreads();

    // ---- phase B: fused sparse scores + online-softmax aggregation ----
    const float scale = 0.088388347648318447f;  // 1/sqrt(128)
    const float sb = sbias_sh;
    float qkr[6];
    #pragma unroll
    for (int k = 0; k < 6; ++k) qkr[k] = qk[lane + 64 * k];

    float m = -INFINITY, ssum = 0.f;
    float ua[6] = {0.f, 0.f, 0.f, 0.f, 0.f, 0.f};

    // one online-softmax step on features f[0..5] (s is wave-uniform)
    auto STEP = [&](const float f0, const float f1, const float f2,
                    const float f3, const float f4, const float f5) {
        float p = qkr[0] * f0 + qkr[1] * f1 + qkr[2] * f2
                + qkr[3] * f3 + qkr[4] * f4 + qkr[5] * f5;
        #pragma unroll
        for (int off = 1; off < 64; off <<= 1) p += __shfl_xor(p, off, 64);
        const float s = (p + sb) * scale;
        if (s <= m) {                       // wave-uniform, common path
            const float e = __expf(s - m);
            ssum += e;
            ua[0] += e * f0;  ua[1] += e * f1;  ua[2] += e * f2;
            ua[3] += e * f3;  ua[4] += e * f4;  ua[5] += e * f5;
        } else {                            // new max: e = exp(s-s) = 1 exactly
            const float corr = __expf(m - s);   // 0 on first neighbor (m=-inf)
            ssum = ssum * corr + 1.f;
            ua[0] = ua[0] * corr + f0;  ua[1] = ua[1] * corr + f1;
            ua[2] = ua[2] * corr + f2;  ua[3] = ua[3] * corr + f3;
            ua[4] = ua[4] * corr + f4;  ua[5] = ua[5] * corr + f5;
            m = s;
        }
    };

    #define LOADF(buf, jj_)  {                                  \
        const int j_ = jl[jj_];                                 \
        const float* xp_ = x   + (size_t)j_ * LAT;              \
        const float* mp_ = mem + (size_t)j_ * LAT;              \
        const float* dp_ = dtv + (size_t)j_ * LAT;              \
        buf##0 = xp_[lane];  buf##1 = xp_[lane + 64];           \
        buf##2 = mp_[lane];  buf##3 = mp_[lane + 64];           \
        buf##4 = dp_[lane];  buf##5 = dp_[lane + 64]; }

    {
        float fa0, fa1, fa2, fa3, fa4, fa5;
        float fb0, fb1, fb2, fb3, fb4, fb5;
        int jj = wave;
        if (jj < nb) LOADF(fa, jj);
        while (jj < nb) {
            const int j2 = jj + 6;
            if (j2 < nb) LOADF(fb, j2);         // prefetch issues before STEP
            STEP(fa0, fa1, fa2, fa3, fa4, fa5);
            jj = j2;
            if (jj >= nb) break;
            const int j3 = jj + 6;
            if (j3 < nb) LOADF(fa, j3);         // prefetch issues before STEP
            STEP(fb0, fb1, fb2, fb3, fb4, fb5);
            jj = j3;
        }
    }
    #undef LOADF

    if (lane == 0) { wm[wave] = m; ws[wave] = ssum; }
    #pragma unroll
    for (int k = 0; k < 6; ++k) upart[wave][lane + 64 * k] = ua[k];
    __syncthreads();

    // ---- phase C: combine 6 per-wave (m, s, u) triples; all 384 threads ----
    {
        float mstar = wm[0];
        #pragma unroll
        for (int w = 1; w < 6; ++w) mstar = fmaxf(mstar, wm[w]);
        float num = 0.f, den = 0.f;
        #pragma unroll
        for (int w = 0; w < 6; ++w) {
            const float c = __expf(wm[w] - mstar);  // 0 for empty waves (wm=-inf)
            num += c * upart[w][tid];
            den += c * ws[w];
        }
        u[tid] = num / den;
    }
    __syncthreads();

    // ---- agg = Wv @ u + bv, 3-way split (INDIM = 3*128) ----
    {
        const float4* wr = (const float4*)(Wv + (size_t)o * INDIM);
        const float4* uv = (const float4*)u;
        const int i0 = pp * 32;
        float acc = 0.f;
        #pragma unroll 4
        for (int i = i0; i < i0 + 32; ++i) acc += dot4(wr[i], uv[i]);
        part[pp * 128 + o] = acc;
    }
    zbuf[LAT + tid] = qin[tid];
    __syncthreads();
    if (tid < 128) zbuf[tid] = bv[tid] + part[tid] + part[128 + tid] + part[256 + tid];
    __syncthreads();

    // ---- h = relu(W1 @ zbuf + b1), 3-way split (128 float4: 43/43/42) ----
    {
        const float4* wr = (const float4*)(W1 + (size_t)o * FFNIN);
        const float4* zv = (const float4*)zbuf;
        const int i0 = pp * 43;
        const int i1 = (pp == 2) ? 128 : i0 + 43;
        float acc = 0.f;
        #pragma unroll 4
        for (int i = i0; i < i1; ++i) acc += dot4(wr[i], zv[i]);
        part[pp * 128 + o] = acc;
    }
    __syncthreads();
    if (tid < 128)
        hbuf[tid] = fmaxf(b1[tid] + part[tid] + part[128 + tid] + part[256 + tid], 0.f);
    __syncthreads();

    // ---- out = W2 @ h + b2, 3-way split (32 float4: 11/11/10) ----
    {
        const float4* wr = (const float4*)(W2 + (size_t)o * LAT);
        const float4* hv = (const float4*)hbuf;
        const int i0 = pp * 11;
        const int i1 = (pp == 2) ? 32 : i0 + 11;
        float acc = 0.f;
        #pragma unroll 4
        for (int i = i0; i < i1; ++i) acc += dot4(wr[i], hv[i]);
        part[pp * 128 + o] = acc;
    }
    __syncthreads();
    if (tid < 128)
        out[(size_t)b * LAT + tid] = b2[tid] + part[tid] + part[128 + tid] + part[256 + tid];
}

extern "C" void kernel_launch(void* const* d_in, const int* in_sizes, int n_in,
                              void* d_out, int out_size, void* d_ws, size_t ws_size,
                              hipStream_t stream) {
    const float*    x    = (const float*)d_in[0];
    const float*    mem  = (const float*)d_in[1];
    const float*    dtv  = (const float*)d_in[2];
    const float*    ttv  = (const float*)d_in[3];
    const uint32_t* mask = (const uint32_t*)d_in[4];  // bool as int32 (verified R1-R3)
    const int*      tidx = (const int*)d_in[5];
    const float*    Wq   = (const float*)d_in[6];
    const float*    bq   = (const float*)d_in[7];
    const float*    Wk   = (const float*)d_in[8];
    const float*    bk   = (const float*)d_in[9];
    const float*    Wv   = (const float*)d_in[10];
    const float*    bv   = (const float*)d_in[11];
    const float*    W1   = (const float*)d_in[12];
    const float*    b1   = (const float*)d_in[13];
    const float*    W2   = (const float*)d_in[14];
    const float*    b2   = (const float*)d_in[15];
    float* out = (float*)d_out;

    fused_graph_attn_kernel<<<BATCH, 384, 0, stream>>>(
        x, mem, dtv, ttv, mask, tidx, Wq, bq, Wk, bk, Wv, bv, W1, b1, W2, b2,
        out);
}